// Round 1
// 383.102 us; speedup vs baseline: 1.3416x; 1.3416x over previous
//
#include <hip/hip_runtime.h>

// PConvLinear: B=2, N=60000, K=16, C_in=64, C_add=3, C_mid=16.
// Phase A (operand-swapped): pconv^T[m][c] = sum_k Wn[k][m] * feat[k][c]
//   via mfma_f32_16x16x16_f16, gather loads go DIRECTLY into B-fragments
//   (no LDS transpose tile, no write->read round trip).
// Phase B: out[16 x 128] = sP @ LWh^T over 34 K-chunks of 32 (f16 MFMA).
#define NPTS  60000
#define NBLK  3750          // blocks per batch (16 points each)
#define FP    1088          // F padded to 34*32 for K-chunking
#define PSTR  1096          // sP row stride (f16): 548 dw, %32=4 -> 2-way (free)

typedef _Float16 f16x4 __attribute__((ext_vector_type(4)));
typedef _Float16 f16x8 __attribute__((ext_vector_type(8)));
typedef float    f32x4 __attribute__((ext_vector_type(4)));

// ---- pre-kernel: linear_weight fp32 [128][1072] -> f16 LWh2[ch=34][o=128][e=32]
// element (o, f): ch = f>>5, e = f&31.  Phase-B load for o-tile o0 is then a
// fully-coalesced 1KB wave transaction: byte = ch*8192 + (o0+ml)*64 + q*16.
__global__ void __launch_bounds__(256)
cvt_lw_kernel(const float* __restrict__ LW, _Float16* __restrict__ LWh) {
    const int o = blockIdx.x;
    for (int f = threadIdx.x; f < FP; f += 256) {
        const float v = (f < 1072) ? LW[o * 1072 + f] : 0.f;
        LWh[(f >> 5) * (128 * 32) + o * 32 + (f & 31)] = (_Float16)v;
    }
}

struct GRegs {
    float fv[4][4];   // [ct][j]: inF[idx(k=q*4+j)][ct*16+ml]
    float wv[4];      // Wn[k=q*4+j][ml]
    float av[4];      // addF[k=q*4+j][ml], ml<3 else 0
};

static __device__ __forceinline__ void issue_gather(
    const float* __restrict__ inF, const float* __restrict__ Wn,
    const float* __restrict__ addF, int bbase, int base_nk,
    int ind_lane, int i, int q, int ml, bool mlo, GRegs& g)
{
    #pragma unroll
    for (int j = 0; j < 4; ++j) {
        const int k   = q * 4 + j;
        const int idx = __shfl(ind_lane, i * 16 + k, 64);   // ds_bpermute
        const float* fp = inF + (bbase + idx) * 64 + ml;
        #pragma unroll
        for (int ct = 0; ct < 4; ++ct)                       // 4 dword loads,
            g.fv[ct][j] = fp[ct * 16];                       // imm offsets 0/64/128/192
        g.wv[j] = Wn[(base_nk + k) * 16 + ml];
        g.av[j] = mlo ? addF[(base_nk + k) * 3 + ml] : 0.f;
    }
}

static __device__ __forceinline__ void compute_point(
    const GRegs& g, _Float16* sProw, int q, int ml, bool mlo)
{
    const f32x4 z4 = {0.f, 0.f, 0.f, 0.f};
    f16x4 aW, bA;
    #pragma unroll
    for (int j = 0; j < 4; ++j) { aW[j] = (_Float16)g.wv[j]; bA[j] = (_Float16)g.av[j]; }

    // D[row=m=q*4+r][col=c=ml]; f = c*16 + m -> d[0..3] are CONSECUTIVE f:
    // one packed ds_write_b64 per MFMA.
    #pragma unroll
    for (int ct = 0; ct < 4; ++ct) {
        f16x4 bF;
        #pragma unroll
        for (int j = 0; j < 4; ++j) bF[j] = (_Float16)g.fv[ct][j];
        const f32x4 d = __builtin_amdgcn_mfma_f32_16x16x16f16(aW, bF, z4, 0, 0, 0);
        f16x4 dh;
        #pragma unroll
        for (int r = 0; r < 4; ++r) dh[r] = (_Float16)d[r];
        *(f16x4*)&sProw[(ct * 16 + ml) * 16 + q * 4] = dh;
    }
    // c-tile 4: c = 64+ml valid for ml<3 (f in [1024,1072))
    const f32x4 d = __builtin_amdgcn_mfma_f32_16x16x16f16(aW, bA, z4, 0, 0, 0);
    if (mlo) {
        f16x4 dh;
        #pragma unroll
        for (int r = 0; r < 4; ++r) dh[r] = (_Float16)d[r];
        *(f16x4*)&sProw[(64 + ml) * 16 + q * 4] = dh;
    }
}

__global__ void __launch_bounds__(256, 4)
pconv_linear_mfma(const float* __restrict__ inF,   // [2][60000][64]
                  const int*   __restrict__ inds,  // [2][60000][16]
                  const float* __restrict__ Wn,    // [2][60000][16][16]
                  const float* __restrict__ addF,  // [2][60000][16][3]
                  const _Float16* __restrict__ LWh,// LWh2[34][128][32] f16 (d_ws)
                  const float* __restrict__ bias,  // [128]
                  float*       __restrict__ out)   // [2][60000][128]
{
    __shared__ __align__(16) _Float16 sP[16 * PSTR];   // pconv tile [p][f], 35 KB

    const int t    = threadIdx.x;
    const int lane = t & 63;
    const int w    = t >> 6;        // wave 0..3
    const int q    = lane >> 4;     // quad 0..3
    const int ml   = lane & 15;
    const bool mlo = (ml < 3);

    const int bid   = blockIdx.x;
    const int b     = bid / NBLK;
    const int n0    = (bid - b * NBLK) * 16;
    const int bbase = b * NPTS;

    // One coalesced load: lane l holds inds[point w*4 + (l>>4)][k = l&15]
    const int ind_lane = inds[(bbase + n0 + w * 4) * 16 + lane];

    // zero the pad columns f in [1072,1088) (nobody writes them in phase A)
    if (t < 128)
        *(unsigned*)&sP[(t >> 3) * PSTR + 1072 + (t & 7) * 2] = 0u;

    // ======== Phase A: direct-to-register gather, depth-2 software pipeline ========
    const int nk0 = (bbase + n0 + w * 4) * 16;
    _Float16* sPw = sP + (w * 4) * PSTR;
    GRegs gA, gB;
    issue_gather(inF, Wn, addF, bbase, nk0,      ind_lane, 0, q, ml, mlo, gA);
    issue_gather(inF, Wn, addF, bbase, nk0 + 16, ind_lane, 1, q, ml, mlo, gB);
    compute_point(gA, sPw,            q, ml, mlo);
    issue_gather(inF, Wn, addF, bbase, nk0 + 32, ind_lane, 2, q, ml, mlo, gA);
    compute_point(gB, sPw + PSTR,     q, ml, mlo);
    issue_gather(inF, Wn, addF, bbase, nk0 + 48, ind_lane, 3, q, ml, mlo, gB);
    compute_point(gA, sPw + 2 * PSTR, q, ml, mlo);
    compute_point(gB, sPw + 3 * PSTR, q, ml, mlo);
    __syncthreads();

    // ======== Phase B: out[16 x 128] = sP @ LWh^T, MFMA over 34 K-chunks ========
    // Wave w owns o-tiles {w*32, w*32+16}. A[row=p=ml][k], B[col=o=ml][k].
    const int o0 = w * 32;
    const float bz0 = bias[o0 + ml];
    const float bz1 = bias[o0 + 16 + ml];
    f32x4 acc0 = {0.f, 0.f, 0.f, 0.f};
    f32x4 acc1 = {0.f, 0.f, 0.f, 0.f};
    const _Float16* aP = sP + ml * PSTR + q * 8;
    const _Float16* bP = LWh + (o0 + ml) * 32 + q * 8;    // + ch*4096 per chunk

    #pragma unroll 4
    for (int ch = 0; ch < 34; ++ch) {
        f16x8 a  = *(const f16x8*)(aP + ch * 32);          // ds_read_b128
        f16x8 b0 = *(const f16x8*)(bP + ch * 4096);        // 1KB coalesced, L2-resident
        f16x8 b1 = *(const f16x8*)(bP + ch * 4096 + 512);  // (+16 o's)
        acc0 = __builtin_amdgcn_mfma_f32_16x16x32_f16(a, b0, acc0, 0, 0, 0);
        acc1 = __builtin_amdgcn_mfma_f32_16x16x32_f16(a, b1, acc1, 0, 0, 0);
    }

    // ======== Epilogue: bias + store (rows p = q*4+r, cols o0+ml / o0+16+ml) ========
    float* obase = out + (bbase + n0 + q * 4) * 128;
    #pragma unroll
    for (int r = 0; r < 4; ++r) {
        obase[r * 128 + o0 + ml]      = acc0[r] + bz0;
        obase[r * 128 + o0 + 16 + ml] = acc1[r] + bz1;
    }
}

extern "C" void kernel_launch(void* const* d_in, const int* in_sizes, int n_in,
                              void* d_out, int out_size, void* d_ws, size_t ws_size,
                              hipStream_t stream)
{
    const float* inF  = (const float*)d_in[0];
    const int*   inds = (const int*)  d_in[1];
    const float* Wn   = (const float*)d_in[2];
    const float* addF = (const float*)d_in[3];
    const float* LW   = (const float*)d_in[4];
    const float* bias = (const float*)d_in[5];
    float* out = (float*)d_out;
    _Float16* LWh = (_Float16*)d_ws;    // 278,528 B of scratch

    cvt_lw_kernel<<<dim3(128), dim3(256), 0, stream>>>(LW, LWh);
    pconv_linear_mfma<<<dim3(2 * NBLK), dim3(256), 0, stream>>>(
        inF, inds, Wn, addF, LWh, bias, out);
}

// Round 2
// 374.904 us; speedup vs baseline: 1.3709x; 1.0219x over previous
//
#include <hip/hip_runtime.h>

// PConvLinear: B=2, N=60000, K=16, C_in=64, C_add=3, C_mid=16.
// Phase A (operand-swapped): pconv^T[m][c] = sum_k Wn[k][m] * feat[k][c]
//   via mfma_f32_16x16x16f16, gathers land DIRECTLY in B-fragments.
// Phase B: out[16 x 128] = sP @ LWh^T over 34 K-chunks of 32 (f16 MFMA).
// This round: 512-thread blocks (8 waves) -> 32 waves/CU occupancy at the
// same 35KB LDS tile; sP slot-XOR swizzle kills the 4-way ds_write conflicts.
#define NPTS  60000
#define NBLK  3750          // blocks per batch (16 points each)
#define FP    1088          // F padded to 34*32 for K-chunking
#define PSTR  1096          // sP row stride (f16): 548 dw, %32=4

typedef _Float16 f16x4 __attribute__((ext_vector_type(4)));
typedef _Float16 f16x8 __attribute__((ext_vector_type(8)));
typedef float    f32x4 __attribute__((ext_vector_type(4)));

// ---- pre-kernel: linear_weight fp32 [128][1072] -> f16 LWh2[ch=34][o=128][e=32]
// element (o, f): ch = f>>5, e = f&31.  Phase-B load for o-tile o0 is then a
// fully-coalesced 1KB wave transaction: byte = ch*8192 + (o0+ml)*64 + q*16.
__global__ void __launch_bounds__(256)
cvt_lw_kernel(const float* __restrict__ LW, _Float16* __restrict__ LWh) {
    const int o = blockIdx.x;
    for (int f = threadIdx.x; f < FP; f += 256) {
        const float v = (f < 1072) ? LW[o * 1072 + f] : 0.f;
        LWh[(f >> 5) * (128 * 32) + o * 32 + (f & 31)] = (_Float16)v;
    }
}

struct GRegs {
    float fv[4][4];   // [ct][j]: inF[idx(k=q*4+j)][ct*16+ml]
    float wv[4];      // Wn[k=q*4+j][ml]
    float av[4];      // addF[k=q*4+j][ml], ml<3 else 0
};

static __device__ __forceinline__ void issue_gather(
    const float* __restrict__ inF, const float* __restrict__ Wn,
    const float* __restrict__ addF, int bbase, int base_nk,
    int ind_lane, int i, int q, int ml, bool mlo, GRegs& g)
{
    #pragma unroll
    for (int j = 0; j < 4; ++j) {
        const int k   = q * 4 + j;
        const int idx = __shfl(ind_lane, i * 16 + k, 64);   // ds_bpermute
        const float* fp = inF + (bbase + idx) * 64 + ml;
        #pragma unroll
        for (int ct = 0; ct < 4; ++ct)                       // 4 dword loads,
            g.fv[ct][j] = fp[ct * 16];                       // imm offsets
        g.wv[j] = Wn[(base_nk + k) * 16 + ml];
        g.av[j] = mlo ? addF[(base_nk + k) * 3 + ml] : 0.f;
    }
}

// D[row=m=q*4+r][col=c=ml]; f = c*16 + m -> d[0..3] are CONSECUTIVE f.
// 8B slot index swizzled: qsw = q ^ (((ml>>2)&1)<<1) (per-thread const),
// spreads the old 4-way same-bank writes (ml stride 32B) to 2-way (free).
static __device__ __forceinline__ void compute_point(
    const GRegs& g, _Float16* sProw, int qsw, int ml, bool mlo)
{
    const f32x4 z4 = {0.f, 0.f, 0.f, 0.f};
    f16x4 aW, bA;
    #pragma unroll
    for (int j = 0; j < 4; ++j) { aW[j] = (_Float16)g.wv[j]; bA[j] = (_Float16)g.av[j]; }

    #pragma unroll
    for (int ct = 0; ct < 4; ++ct) {
        f16x4 bF;
        #pragma unroll
        for (int j = 0; j < 4; ++j) bF[j] = (_Float16)g.fv[ct][j];
        const f32x4 d = __builtin_amdgcn_mfma_f32_16x16x16f16(aW, bF, z4, 0, 0, 0);
        f16x4 dh;
        #pragma unroll
        for (int r = 0; r < 4; ++r) dh[r] = (_Float16)d[r];
        *(f16x4*)&sProw[(ct * 16 + ml) * 16 + qsw * 4] = dh;
    }
    // c-tile 4: c = 64+ml valid for ml<3 (f in [1024,1072)); ml<3 -> qsw==q,
    // and ((64+ml)>>2)&1 == 0 so this row is unswizzled — consistent.
    const f32x4 d = __builtin_amdgcn_mfma_f32_16x16x16f16(aW, bA, z4, 0, 0, 0);
    if (mlo) {
        f16x4 dh;
        #pragma unroll
        for (int r = 0; r < 4; ++r) dh[r] = (_Float16)d[r];
        *(f16x4*)&sProw[(64 + ml) * 16 + qsw * 4] = dh;
    }
}

__global__ void __launch_bounds__(512, 8)
pconv_linear_mfma(const float* __restrict__ inF,   // [2][60000][64]
                  const int*   __restrict__ inds,  // [2][60000][16]
                  const float* __restrict__ Wn,    // [2][60000][16][16]
                  const float* __restrict__ addF,  // [2][60000][16][3]
                  const _Float16* __restrict__ LWh,// LWh2[34][128][32] f16 (d_ws)
                  const float* __restrict__ bias,  // [128]
                  float*       __restrict__ out)   // [2][60000][128]
{
    __shared__ __align__(16) _Float16 sP[16 * PSTR];   // pconv tile [p][f], 35 KB

    const int t    = threadIdx.x;
    const int lane = t & 63;
    const int w    = t >> 6;        // wave 0..7
    const int q    = lane >> 4;     // quad 0..3
    const int ml   = lane & 15;
    const bool mlo = (ml < 3);
    const int qsw  = q ^ (((ml >> 2) & 1) << 1);

    const int bid   = blockIdx.x;
    const int b     = bid / NBLK;
    const int n0    = (bid - b * NBLK) * 16;
    const int bbase = b * NPTS;

    // lane l (l<32 real) holds inds[point w*2 + (l>>4)][k = l&15]
    const int ind_lane = inds[(bbase + n0 + w * 2) * 16 + (lane & 31)];

    // zero the pad rows c=67 i.e. f in [1072,1088) (x2(c=67)=0: unswizzled)
    if (t < 256)
        sP[(t >> 4) * PSTR + 1072 + (t & 15)] = (_Float16)0.f;

    // ======== Phase A: direct-to-register gather, both points fully in flight ========
    const int nk0 = (bbase + n0 + w * 2) * 16;
    _Float16* sPw = sP + (w * 2) * PSTR;
    GRegs g0, g1;
    issue_gather(inF, Wn, addF, bbase, nk0,      ind_lane, 0, q, ml, mlo, g0);
    issue_gather(inF, Wn, addF, bbase, nk0 + 16, ind_lane, 1, q, ml, mlo, g1);
    compute_point(g0, sPw,        qsw, ml, mlo);
    compute_point(g1, sPw + PSTR, qsw, ml, mlo);
    __syncthreads();

    // ======== Phase B: out[16 x 128] = sP @ LWh^T, MFMA over 34 K-chunks ========
    // Wave w owns o-tile o0 = w*16. A[row=p=ml][k], B[col=o=ml][k].
    // Read-side of the slot swizzle: logical f16x8 at f = ch*32 + q*8 sits at
    // ml*PSTR + ch*32 + (q>>1)*16 + ((q&1) ^ ((ch>>1)&1))*8.
    const int o0 = w * 16;
    const float bz = bias[o0 + ml];
    f32x4 acc = {0.f, 0.f, 0.f, 0.f};
    const _Float16* aP = sP + ml * PSTR + (q >> 1) * 16 + (q & 1) * 8;
    const int flip = (q & 1) ? -8 : 8;                     // f16 units
    const _Float16* bP = LWh + (o0 + ml) * 32 + q * 8;     // + ch*4096 per chunk

    #pragma unroll 4
    for (int ch = 0; ch < 34; ++ch) {
        const int off = ch * 32 + ((ch & 2) ? flip : 0);
        f16x8 a = *(const f16x8*)(aP + off);               // ds_read_b128
        f16x8 b = *(const f16x8*)(bP + ch * 4096);         // 1KB coalesced, L2-resident
        acc = __builtin_amdgcn_mfma_f32_16x16x32_f16(a, b, acc, 0, 0, 0);
    }

    // ======== Epilogue: bias + store (rows p = q*4+r, cols o0+ml) ========
    float* obase = out + (bbase + n0 + q * 4) * 128 + o0 + ml;
    #pragma unroll
    for (int r = 0; r < 4; ++r)
        obase[r * 128] = acc[r] + bz;
}

extern "C" void kernel_launch(void* const* d_in, const int* in_sizes, int n_in,
                              void* d_out, int out_size, void* d_ws, size_t ws_size,
                              hipStream_t stream)
{
    const float* inF  = (const float*)d_in[0];
    const int*   inds = (const int*)  d_in[1];
    const float* Wn   = (const float*)d_in[2];
    const float* addF = (const float*)d_in[3];
    const float* LW   = (const float*)d_in[4];
    const float* bias = (const float*)d_in[5];
    float* out = (float*)d_out;
    _Float16* LWh = (_Float16*)d_ws;    // 278,528 B of scratch

    cvt_lw_kernel<<<dim3(128), dim3(256), 0, stream>>>(LW, LWh);
    pconv_linear_mfma<<<dim3(2 * NBLK), dim3(512), 0, stream>>>(
        inF, inds, Wn, addF, LWh, bias, out);
}

// Round 3
// 346.159 us; speedup vs baseline: 1.4848x; 1.0830x over previous
//
#include <hip/hip_runtime.h>

// PConvLinear: B=2, N=60000, K=16, C_in=64, C_add=3, C_mid=16.
// Phase A (operand-swapped): pconv^T[m][c] = sum_k Wn[k][m] * feat[k][c]
//   via mfma_f32_16x16x16f16, gathers land DIRECTLY in B-fragments.
// Phase B: out[32 x 128] = sP @ LWh^T over 34 K-chunks of 32 (f16 MFMA).
// This round: 32 points per block (two 16-pt sub-tiles) so each LWh
// b-fragment load feeds TWO MFMAs -> halves the dominant L2 stream.
// sP = 70KB dynamic LDS (hipFuncSetAttribute opt-in), 2 blocks/CU.
#define NPTS  60000
#define NBLK  1875          // blocks per batch (32 points each)
#define FP    1088          // F padded to 34*32 for K-chunking
#define PSTR  1096          // sP row stride (f16): 548 dw, %32=4
#define SPBYTES (32 * PSTR * 2)   // 70,144 B

typedef _Float16 f16x4 __attribute__((ext_vector_type(4)));
typedef _Float16 f16x8 __attribute__((ext_vector_type(8)));
typedef float    f32x4 __attribute__((ext_vector_type(4)));

// ---- pre-kernel: linear_weight fp32 [128][1072] -> f16 LWh2[ch=34][o=128][e=32]
// Phase-B load for o-tile o0 is a fully-coalesced 1KB wave transaction:
// byte = ch*8192 + (o0+ml)*64 + q*16.
__global__ void __launch_bounds__(256)
cvt_lw_kernel(const float* __restrict__ LW, _Float16* __restrict__ LWh) {
    const int o = blockIdx.x;
    for (int f = threadIdx.x; f < FP; f += 256) {
        const float v = (f < 1072) ? LW[o * 1072 + f] : 0.f;
        LWh[(f >> 5) * (128 * 32) + o * 32 + (f & 31)] = (_Float16)v;
    }
}

struct GRegs {
    float fv[4][4];   // [ct][j]: inF[idx(k=q*4+j)][ct*16+ml]
    float wv[4];      // Wn[k=q*4+j][ml]
    float av[4];      // addF[k=q*4+j][ml], ml<3 else 0
};

static __device__ __forceinline__ void issue_gather(
    const float* __restrict__ inF, const float* __restrict__ Wn,
    const float* __restrict__ addF, int bbase, int base_nk,
    int ind_lane, int i, int q, int ml, bool mlo, GRegs& g)
{
    #pragma unroll
    for (int j = 0; j < 4; ++j) {
        const int k   = q * 4 + j;
        const int idx = __shfl(ind_lane, i * 16 + k, 64);   // ds_bpermute
        const float* fp = inF + (bbase + idx) * 64 + ml;
        #pragma unroll
        for (int ct = 0; ct < 4; ++ct)                       // 4 dword loads,
            g.fv[ct][j] = fp[ct * 16];                       // imm offsets
        g.wv[j] = Wn[(base_nk + k) * 16 + ml];
        g.av[j] = mlo ? addF[(base_nk + k) * 3 + ml] : 0.f;
    }
}

// D[row=m=q*4+r][col=c=ml]; f = c*16 + m -> d[0..3] are CONSECUTIVE f.
// 8B slot index swizzled: qsw = q ^ (((ml>>2)&1)<<1) (per-thread const).
static __device__ __forceinline__ void compute_point(
    const GRegs& g, _Float16* sProw, int qsw, int ml, bool mlo)
{
    const f32x4 z4 = {0.f, 0.f, 0.f, 0.f};
    f16x4 aW, bA;
    #pragma unroll
    for (int j = 0; j < 4; ++j) { aW[j] = (_Float16)g.wv[j]; bA[j] = (_Float16)g.av[j]; }

    #pragma unroll
    for (int ct = 0; ct < 4; ++ct) {
        f16x4 bF;
        #pragma unroll
        for (int j = 0; j < 4; ++j) bF[j] = (_Float16)g.fv[ct][j];
        const f32x4 d = __builtin_amdgcn_mfma_f32_16x16x16f16(aW, bF, z4, 0, 0, 0);
        f16x4 dh;
        #pragma unroll
        for (int r = 0; r < 4; ++r) dh[r] = (_Float16)d[r];
        *(f16x4*)&sProw[(ct * 16 + ml) * 16 + qsw * 4] = dh;
    }
    // c-tile 4: c = 64+ml valid for ml<3 (f in [1024,1072)); ml<3 -> qsw==q.
    const f32x4 d = __builtin_amdgcn_mfma_f32_16x16x16f16(aW, bA, z4, 0, 0, 0);
    if (mlo) {
        f16x4 dh;
        #pragma unroll
        for (int r = 0; r < 4; ++r) dh[r] = (_Float16)d[r];
        *(f16x4*)&sProw[(64 + ml) * 16 + qsw * 4] = dh;
    }
}

__global__ void __launch_bounds__(512, 4)
pconv_linear_mfma(const float* __restrict__ inF,   // [2][60000][64]
                  const int*   __restrict__ inds,  // [2][60000][16]
                  const float* __restrict__ Wn,    // [2][60000][16][16]
                  const float* __restrict__ addF,  // [2][60000][16][3]
                  const _Float16* __restrict__ LWh,// LWh2[34][128][32] f16 (d_ws)
                  const float* __restrict__ bias,  // [128]
                  float*       __restrict__ out)   // [2][60000][128]
{
    extern __shared__ __align__(16) _Float16 sP[];   // [32][PSTR] f16, 70,144 B

    const int t    = threadIdx.x;
    const int lane = t & 63;
    const int w    = t >> 6;        // wave 0..7
    const int q    = lane >> 4;     // quad 0..3
    const int ml   = lane & 15;
    const bool mlo = (ml < 3);
    const int qsw  = q ^ (((ml >> 2) & 1) << 1);

    const int bid   = blockIdx.x;
    const int b     = bid / NBLK;
    const int n0    = (bid - b * NBLK) * 32;
    const int bbase = b * NPTS;

    // lane l holds inds[point w*4 + (l>>4)][k = l&15]
    const int ind_lane = inds[(bbase + n0 + w * 4) * 16 + lane];

    // zero the pad cols f in [1072,1088) for all 32 rows (512 threads, 1 f16 each)
    sP[(t >> 4) * PSTR + 1072 + (t & 15)] = (_Float16)0.f;

    // ======== Phase A: direct-to-register gather, depth-2 software pipeline ========
    const int nk0 = (bbase + n0 + w * 4) * 16;
    _Float16* sPw = sP + (w * 4) * PSTR;
    GRegs g0, g1;
    issue_gather(inF, Wn, addF, bbase, nk0,      ind_lane, 0, q, ml, mlo, g0);
    issue_gather(inF, Wn, addF, bbase, nk0 + 16, ind_lane, 1, q, ml, mlo, g1);
    compute_point(g0, sPw,            qsw, ml, mlo);
    issue_gather(inF, Wn, addF, bbase, nk0 + 32, ind_lane, 2, q, ml, mlo, g0);
    compute_point(g1, sPw + PSTR,     qsw, ml, mlo);
    issue_gather(inF, Wn, addF, bbase, nk0 + 48, ind_lane, 3, q, ml, mlo, g1);
    compute_point(g0, sPw + 2 * PSTR, qsw, ml, mlo);
    compute_point(g1, sPw + 3 * PSTR, qsw, ml, mlo);
    __syncthreads();

    // ======== Phase B: out[32 x 128] = sP @ LWh^T, MFMA over 34 K-chunks ========
    // Wave w owns o-tile o0 = w*16 for BOTH 16-pt sub-tiles: one b load -> 2 MFMAs.
    // Read-side of the slot swizzle: logical f16x8 at f = ch*32 + q*8 sits at
    // row*PSTR + ch*32 + (q>>1)*16 + ((q&1) ^ ((ch>>1)&1))*8.
    const int o0 = w * 16;
    const float bz = bias[o0 + ml];
    f32x4 acc0 = {0.f, 0.f, 0.f, 0.f};
    f32x4 acc1 = {0.f, 0.f, 0.f, 0.f};
    const _Float16* aP0 = sP + ml * PSTR + (q >> 1) * 16 + (q & 1) * 8;
    const _Float16* aP1 = aP0 + 16 * PSTR;
    const int flip = (q & 1) ? -8 : 8;                     // f16 units
    const _Float16* bP = LWh + (o0 + ml) * 32 + q * 8;     // + ch*4096 per chunk

    #pragma unroll 2
    for (int ch = 0; ch < 34; ++ch) {
        const int off = ch * 32 + ((ch & 2) ? flip : 0);
        f16x8 bf = *(const f16x8*)(bP + ch * 4096);        // 1KB coalesced, L2-resident
        f16x8 a0 = *(const f16x8*)(aP0 + off);             // ds_read_b128
        f16x8 a1 = *(const f16x8*)(aP1 + off);
        acc0 = __builtin_amdgcn_mfma_f32_16x16x32_f16(a0, bf, acc0, 0, 0, 0);
        acc1 = __builtin_amdgcn_mfma_f32_16x16x32_f16(a1, bf, acc1, 0, 0, 0);
    }

    // ======== Epilogue: bias + store (rows p = q*4+r and +16, cols o0+ml) ========
    float* ob = out + (bbase + n0 + q * 4) * 128 + o0 + ml;
    #pragma unroll
    for (int r = 0; r < 4; ++r)
        ob[r * 128] = acc0[r] + bz;
    ob += 16 * 128;
    #pragma unroll
    for (int r = 0; r < 4; ++r)
        ob[r * 128] = acc1[r] + bz;
}

extern "C" void kernel_launch(void* const* d_in, const int* in_sizes, int n_in,
                              void* d_out, int out_size, void* d_ws, size_t ws_size,
                              hipStream_t stream)
{
    const float* inF  = (const float*)d_in[0];
    const int*   inds = (const int*)  d_in[1];
    const float* Wn   = (const float*)d_in[2];
    const float* addF = (const float*)d_in[3];
    const float* LW   = (const float*)d_in[4];
    const float* bias = (const float*)d_in[5];
    float* out = (float*)d_out;
    _Float16* LWh = (_Float16*)d_ws;    // 278,528 B of scratch

    // opt-in to >64KB dynamic LDS (host-side attr set, graph-capture safe)
    hipFuncSetAttribute((const void*)pconv_linear_mfma,
                        hipFuncAttributeMaxDynamicSharedMemorySize, SPBYTES);

    cvt_lw_kernel<<<dim3(128), dim3(256), 0, stream>>>(LW, LWh);
    pconv_linear_mfma<<<dim3(2 * NBLK), dim3(512), SPBYTES, stream>>>(
        inF, inds, Wn, addF, LWh, bias, out);
}